// Round 2
// baseline (392.810 us; speedup 1.0000x reference)
//
#include <hip/hip_runtime.h>
#include <math.h>

#define G 8  // tokens per round; LDS = 8*4KB + ~1.4KB -> 4 blocks/CU

__device__ __forceinline__ float sigmoidf_(float s) {
    return 1.0f / (1.0f + __expf(-s));
}

// v + (v cross-lane-moved by DPP ctrl). quad_perm 0xB1 = xor1, 0x4E = xor2,
// 0x128 = row_ror:8 = exact xor8 within each 16-lane row. VALU pipe, not LDS.
template <int CTRL>
__device__ __forceinline__ float dpp_add(float v) {
    int m = __builtin_amdgcn_update_dpp(0, __float_as_int(v), CTRL, 0xF, 0xF, true);
    return v + __int_as_float(m);
}

__global__ __launch_bounds__(256, 4)
void fused_route_mix(const float* __restrict__ x,
                     const float* __restrict__ scale,
                     const float* __restrict__ w_pre,
                     const float* __restrict__ w_post,
                     const float* __restrict__ w_res,
                     const float* __restrict__ ap_p,
                     const float* __restrict__ apo_p,
                     const float* __restrict__ ar_p,
                     const float* __restrict__ b_pre,
                     const float* __restrict__ b_post,
                     const float* __restrict__ b_res,
                     float* __restrict__ out,
                     int rounds)
{
    __shared__ __align__(16) float xs[G * 1024];
    __shared__ float hraw[G * 24];
    __shared__ float sslds[G];
    __shared__ __align__(16) float Mlds[G * 16];

    const int t = threadIdx.x;
    const int w = t >> 6;   // wave 0..3, owns rows 6w..6w+5
    const int l = t & 63;

    // ---- once per block: weights in regs, scale folded. lane owns float4s {64m+l}.
    float wreg[6][16];
    {
        const float4* sc4 = (const float4*)scale;
        float4 scl[4];
        #pragma unroll
        for (int m = 0; m < 4; ++m) scl[m] = sc4[64 * m + l];
        #pragma unroll
        for (int rr = 0; rr < 6; ++rr) {
            const int k = 6 * w + rr;
            const float* wp = (k < 4) ? (w_pre + (size_t)k * 1024)
                            : (k < 8) ? (w_post + (size_t)(k - 4) * 1024)
                                      : (w_res + (size_t)(k - 8) * 1024);
            const float4* wp4 = (const float4*)wp;
            #pragma unroll
            for (int m = 0; m < 4; ++m) {
                const float4 v = wp4[64 * m + l];
                wreg[rr][m * 4 + 0] = v.x * scl[m].x;
                wreg[rr][m * 4 + 1] = v.y * scl[m].y;
                wreg[rr][m * 4 + 2] = v.z * scl[m].z;
                wreg[rr][m * 4 + 3] = v.w * scl[m].w;
            }
        }
    }

    const float a_pre = ap_p[0], a_post = apo_p[0], a_res = ar_p[0];
    float4* xs4 = (float4*)xs;

    for (int r = blockIdx.x; r < rounds; r += gridDim.x) {
        const size_t base = (size_t)r * (G * 1024);

        // ---- phase 1: stage x ----
        const float4* __restrict__ xg4 = (const float4*)(x + base);
        #pragma unroll
        for (int i = 0; i < G; ++i)
            xs4[i * 256 + t] = xg4[i * 256 + t];
        __syncthreads();

        // ---- phase 2: 6 dots/wave + sumsq per token ----
        for (int i = 0; i < G; ++i) {
            float p0 = 0.f, p1 = 0.f, p2 = 0.f, p3 = 0.f, p4 = 0.f, p5 = 0.f;
            float ssa = 0.f;
            const float4* xi4 = xs4 + i * 256 + l;
            #pragma unroll
            for (int m = 0; m < 4; ++m) {
                const float4 xv = xi4[m * 64];   // ds_read_b128, conflict-free
                const float xe[4] = {xv.x, xv.y, xv.z, xv.w};
                #pragma unroll
                for (int e = 0; e < 4; ++e) {
                    const float xf = xe[e];
                    const int c = m * 4 + e;
                    p0 = fmaf(xf, wreg[0][c], p0);
                    p1 = fmaf(xf, wreg[1][c], p1);
                    p2 = fmaf(xf, wreg[2][c], p2);
                    p3 = fmaf(xf, wreg[3][c], p3);
                    p4 = fmaf(xf, wreg[4][c], p4);
                    p5 = fmaf(xf, wreg[5][c], p5);
                    ssa = fmaf(xf, xf, ssa);
                }
            }
            // folded butterfly: 8 values {p0..p5, ss, 0} -> lane k holds value k&7.
            // level 1 (xor1, DPP quad_perm)
            const float a0 = dpp_add<0xB1>(p0), a1 = dpp_add<0xB1>(p1);
            const float a2 = dpp_add<0xB1>(p2), a3 = dpp_add<0xB1>(p3);
            const float a4 = dpp_add<0xB1>(p4), a5 = dpp_add<0xB1>(p5);
            const float a6 = dpp_add<0xB1>(ssa);
            const bool b0 = l & 1;
            const float q0 = b0 ? a1 : a0;
            const float q1 = b0 ? a3 : a2;
            const float q2 = b0 ? a5 : a4;
            const float q3 = b0 ? 0.0f : a6;
            // level 2 (xor2, DPP quad_perm)
            const float c0 = dpp_add<0x4E>(q0), c1 = dpp_add<0x4E>(q1);
            const float c2 = dpp_add<0x4E>(q2), c3 = dpp_add<0x4E>(q3);
            const bool b1 = l & 2;
            const float r0 = b1 ? c1 : c0;
            const float r1 = b1 ? c3 : c2;
            // level 3 (xor4, DS shuffle x2)
            const float d0 = r0 + __shfl_xor(r0, 4);
            const float d1 = r1 + __shfl_xor(r1, 4);
            float s = (l & 4) ? d1 : d0;
            // level 4 (xor8 via DPP row_ror:8), levels 5-6 (DS shuffle)
            s = dpp_add<0x128>(s);
            s += __shfl_xor(s, 16);
            s += __shfl_xor(s, 32);

            const int k = l & 7;
            if (k < 6 && l < 8) hraw[i * 24 + 6 * w + k] = s;
            if (w == 0 && l == 6) sslds[i] = s;
        }
        __syncthreads();

        // ---- phase 3: nonlinearity + sinkhorn, token-per-lane ----
        if (t < G) {
            const int tk = t;
            const float inv = rsqrtf(sslds[tk] * (1.0f / 1024.0f) + 1e-5f);
            float hr[24];
            #pragma unroll
            for (int k2 = 0; k2 < 24; ++k2) hr[k2] = hraw[tk * 24 + k2];

            float hpre[4], hpost[4];
            #pragma unroll
            for (int j = 0; j < 4; ++j)
                hpre[j] = sigmoidf_(fmaf(a_pre * inv, hr[j], b_pre[j]));
            #pragma unroll
            for (int i = 0; i < 4; ++i)
                hpost[i] = 2.0f * sigmoidf_(fmaf(a_post * inv, hr[4 + i], b_post[i]));

            float K[4][4];
            float mx = -1e30f;
            #pragma unroll
            for (int i = 0; i < 4; ++i)
                #pragma unroll
                for (int j = 0; j < 4; ++j) {
                    const float vv = fmaf(a_res * inv, hr[8 + 4 * i + j], b_res[4 * i + j]);
                    K[i][j] = vv;
                    mx = fmaxf(mx, vv);
                }
            #pragma unroll
            for (int i = 0; i < 4; ++i)
                #pragma unroll
                for (int j = 0; j < 4; ++j)
                    K[i][j] = __expf(K[i][j] - mx);

            float u[4] = {1.f, 1.f, 1.f, 1.f};
            float v[4] = {1.f, 1.f, 1.f, 1.f};
            for (int it = 0; it < 20; ++it) {
                #pragma unroll
                for (int j = 0; j < 4; ++j) {
                    const float S = u[0] * K[0][j] + u[1] * K[1][j]
                                  + u[2] * K[2][j] + u[3] * K[3][j];
                    v[j] = v[j] * __builtin_amdgcn_rcpf(fmaf(v[j], S, 1e-8f));
                }
                #pragma unroll
                for (int i = 0; i < 4; ++i) {
                    const float T = K[i][0] * v[0] + K[i][1] * v[1]
                                  + K[i][2] * v[2] + K[i][3] * v[3];
                    u[i] = u[i] * __builtin_amdgcn_rcpf(fmaf(u[i], T, 1e-8f));
                }
            }
            #pragma unroll
            for (int i = 0; i < 4; ++i)
                #pragma unroll
                for (int j = 0; j < 4; ++j)
                    Mlds[tk * 16 + 4 * i + j] =
                        fmaf(u[i] * K[i][j], v[j], hpost[i] * hpre[j]);
        }
        __syncthreads();

        // ---- phase 4: mixing ----
        for (int i = 0; i < G; ++i) {
            const float4 m4 = ((const float4*)Mlds)[i * 4 + w];
            const float4* xt = xs4 + i * 256;
            const float4 a0 = xt[0 * 64 + l];
            const float4 a1 = xt[1 * 64 + l];
            const float4 a2 = xt[2 * 64 + l];
            const float4 a3 = xt[3 * 64 + l];
            float4 o;
            o.x = m4.x * a0.x + m4.y * a1.x + m4.z * a2.x + m4.w * a3.x;
            o.y = m4.x * a0.y + m4.y * a1.y + m4.z * a2.y + m4.w * a3.y;
            o.z = m4.x * a0.z + m4.y * a1.z + m4.z * a2.z + m4.w * a3.z;
            o.w = m4.x * a0.w + m4.y * a1.w + m4.z * a2.w + m4.w * a3.w;
            ((float4*)(out + base))[i * 256 + w * 64 + l] = o;
        }
        __syncthreads();
    }
}

extern "C" void kernel_launch(void* const* d_in, const int* in_sizes, int n_in,
                              void* d_out, int out_size, void* d_ws, size_t ws_size,
                              hipStream_t stream) {
    const float* x      = (const float*)d_in[0];
    const float* scale  = (const float*)d_in[1];
    const float* w_pre  = (const float*)d_in[2];
    const float* w_post = (const float*)d_in[3];
    const float* w_res  = (const float*)d_in[4];
    const float* a_pre  = (const float*)d_in[5];
    const float* a_post = (const float*)d_in[6];
    const float* a_res  = (const float*)d_in[7];
    const float* b_pre  = (const float*)d_in[8];
    const float* b_post = (const float*)d_in[9];
    const float* b_res  = (const float*)d_in[10];
    float* out = (float*)d_out;

    const int tokens = in_sizes[0] / 1024;   // B*T
    const int rounds = tokens / G;
    const int grid = rounds < 1024 ? rounds : 1024;

    fused_route_mix<<<grid, 256, 0, stream>>>(
        x, scale, w_pre, w_post, w_res,
        a_pre, a_post, a_res, b_pre, b_post, b_res,
        out, rounds);
}

// Round 4
// 311.570 us; speedup vs baseline: 1.2607x; 1.2607x over previous
//
#include <hip/hip_runtime.h>
#include <math.h>

#define G 8  // tokens per round; LDS = 8*4KB + ~1.4KB -> 4 blocks/CU (VGPR permitting)

typedef float nfloat4 __attribute__((ext_vector_type(4)));  // native vec for nontemporal builtins

__device__ __forceinline__ float sigmoidf_(float s) {
    return 1.0f / (1.0f + __expf(-s));
}

// v + (v cross-lane-moved by DPP ctrl). quad_perm 0xB1 = xor1, 0x4E = xor2,
// 0x128 = row_ror:8 = exact xor8 within each 16-lane row. VALU pipe, not LDS.
template <int CTRL>
__device__ __forceinline__ float dpp_add(float v) {
    int m = __builtin_amdgcn_update_dpp(0, __float_as_int(v), CTRL, 0xF, 0xF, true);
    return v + __int_as_float(m);
}

__global__ __launch_bounds__(256, 2)   // (256,4) caused VGPR=64 + scratch spill (R2)
void fused_route_mix(const float* __restrict__ x,
                     const float* __restrict__ scale,
                     const float* __restrict__ w_pre,
                     const float* __restrict__ w_post,
                     const float* __restrict__ w_res,
                     const float* __restrict__ ap_p,
                     const float* __restrict__ apo_p,
                     const float* __restrict__ ar_p,
                     const float* __restrict__ b_pre,
                     const float* __restrict__ b_post,
                     const float* __restrict__ b_res,
                     float* __restrict__ out,
                     int rounds)
{
    __shared__ __align__(16) float xs[G * 1024];
    __shared__ float hraw[G * 24];
    __shared__ float sslds[G];
    __shared__ __align__(16) float Mlds[G * 16];

    const int t = threadIdx.x;
    const int w = t >> 6;   // wave 0..3, owns rows 6w..6w+5
    const int l = t & 63;

    // ---- once per block: weights in regs, scale folded (R1-proven scalar path) ----
    float wreg[6][16];
    {
        float scl[16];
        #pragma unroll
        for (int m = 0; m < 16; ++m) scl[m] = scale[l + 64 * m];
        #pragma unroll
        for (int rr = 0; rr < 6; ++rr) {
            const int k = 6 * w + rr;
            const float* wp = (k < 4) ? (w_pre + (size_t)k * 1024)
                            : (k < 8) ? (w_post + (size_t)(k - 4) * 1024)
                                      : (w_res + (size_t)(k - 8) * 1024);
            #pragma unroll
            for (int m = 0; m < 16; ++m)
                wreg[rr][m] = wp[l + 64 * m] * scl[m];
        }
    }

    const float a_pre = ap_p[0], a_post = apo_p[0], a_res = ar_p[0];
    float4* xs4 = (float4*)xs;
    nfloat4* xsn = (nfloat4*)xs;

    for (int r = blockIdx.x; r < rounds; r += gridDim.x) {
        const size_t base = (size_t)r * (G * 1024);

        // ---- phase 1: stage x (nontemporal: read-once data, keep L2 for weights) ----
        const nfloat4* __restrict__ xg4 = (const nfloat4*)(x + base);
        #pragma unroll
        for (int i = 0; i < G; ++i)
            xsn[i * 256 + t] = __builtin_nontemporal_load(xg4 + i * 256 + t);
        __syncthreads();

        // ---- phase 2: 6 dots/wave + sumsq per token ----
        for (int i = 0; i < G; ++i) {
            float p0 = 0.f, p1 = 0.f, p2 = 0.f, p3 = 0.f, p4 = 0.f, p5 = 0.f;
            float ssa = 0.f;
            const float4* xi4 = xs4 + i * 256 + l;
            #pragma unroll
            for (int m = 0; m < 4; ++m) {
                const float4 xv = xi4[m * 64];   // ds_read_b128, conflict-free
                const float xe[4] = {xv.x, xv.y, xv.z, xv.w};
                #pragma unroll
                for (int e = 0; e < 4; ++e) {
                    const float xf = xe[e];
                    const int c = m * 4 + e;
                    p0 = fmaf(xf, wreg[0][c], p0);
                    p1 = fmaf(xf, wreg[1][c], p1);
                    p2 = fmaf(xf, wreg[2][c], p2);
                    p3 = fmaf(xf, wreg[3][c], p3);
                    p4 = fmaf(xf, wreg[4][c], p4);
                    p5 = fmaf(xf, wreg[5][c], p5);
                    ssa = fmaf(xf, xf, ssa);
                }
            }
            // folded butterfly: 8 values {p0..p5, ss, 0} -> lane k holds value k&7.
            const float a0 = dpp_add<0xB1>(p0), a1 = dpp_add<0xB1>(p1);
            const float a2 = dpp_add<0xB1>(p2), a3 = dpp_add<0xB1>(p3);
            const float a4 = dpp_add<0xB1>(p4), a5 = dpp_add<0xB1>(p5);
            const float a6 = dpp_add<0xB1>(ssa);
            const bool b0 = l & 1;
            const float q0 = b0 ? a1 : a0;
            const float q1 = b0 ? a3 : a2;
            const float q2 = b0 ? a5 : a4;
            const float q3 = b0 ? 0.0f : a6;
            const float c0 = dpp_add<0x4E>(q0), c1 = dpp_add<0x4E>(q1);
            const float c2 = dpp_add<0x4E>(q2), c3 = dpp_add<0x4E>(q3);
            const bool b1 = l & 2;
            const float r0 = b1 ? c1 : c0;
            const float r1 = b1 ? c3 : c2;
            const float d0 = r0 + __shfl_xor(r0, 4);
            const float d1 = r1 + __shfl_xor(r1, 4);
            float s = (l & 4) ? d1 : d0;
            s = dpp_add<0x128>(s);   // xor8 via row_ror:8
            s += __shfl_xor(s, 16);
            s += __shfl_xor(s, 32);

            const int k = l & 7;
            if (k < 6 && l < 8) hraw[i * 24 + 6 * w + k] = s;
            if (w == 0 && l == 6) sslds[i] = s;
        }
        __syncthreads();

        // ---- phase 3: nonlinearity + sinkhorn, token-per-lane ----
        if (t < G) {
            const int tk = t;
            const float inv = rsqrtf(sslds[tk] * (1.0f / 1024.0f) + 1e-5f);
            float hr[24];
            #pragma unroll
            for (int k2 = 0; k2 < 24; ++k2) hr[k2] = hraw[tk * 24 + k2];

            float hpre[4], hpost[4];
            #pragma unroll
            for (int j = 0; j < 4; ++j)
                hpre[j] = sigmoidf_(fmaf(a_pre * inv, hr[j], b_pre[j]));
            #pragma unroll
            for (int i = 0; i < 4; ++i)
                hpost[i] = 2.0f * sigmoidf_(fmaf(a_post * inv, hr[4 + i], b_post[i]));

            float K[4][4];
            float mx = -1e30f;
            #pragma unroll
            for (int i = 0; i < 4; ++i)
                #pragma unroll
                for (int j = 0; j < 4; ++j) {
                    const float vv = fmaf(a_res * inv, hr[8 + 4 * i + j], b_res[4 * i + j]);
                    K[i][j] = vv;
                    mx = fmaxf(mx, vv);
                }
            #pragma unroll
            for (int i = 0; i < 4; ++i)
                #pragma unroll
                for (int j = 0; j < 4; ++j)
                    K[i][j] = __expf(K[i][j] - mx);

            float u[4] = {1.f, 1.f, 1.f, 1.f};
            float v[4] = {1.f, 1.f, 1.f, 1.f};
            for (int it = 0; it < 20; ++it) {
                #pragma unroll
                for (int j = 0; j < 4; ++j) {
                    const float S = u[0] * K[0][j] + u[1] * K[1][j]
                                  + u[2] * K[2][j] + u[3] * K[3][j];
                    v[j] = v[j] * __builtin_amdgcn_rcpf(fmaf(v[j], S, 1e-8f));
                }
                #pragma unroll
                for (int i = 0; i < 4; ++i) {
                    const float T = K[i][0] * v[0] + K[i][1] * v[1]
                                  + K[i][2] * v[2] + K[i][3] * v[3];
                    u[i] = u[i] * __builtin_amdgcn_rcpf(fmaf(u[i], T, 1e-8f));
                }
            }
            #pragma unroll
            for (int i = 0; i < 4; ++i)
                #pragma unroll
                for (int j = 0; j < 4; ++j)
                    Mlds[tk * 16 + 4 * i + j] =
                        fmaf(u[i] * K[i][j], v[j], hpost[i] * hpre[j]);
        }
        __syncthreads();

        // ---- phase 4: mixing (nontemporal stores: out never re-read) ----
        for (int i = 0; i < G; ++i) {
            const float4 m4 = ((const float4*)Mlds)[i * 4 + w];
            const float4* xt = xs4 + i * 256;
            const float4 a0 = xt[0 * 64 + l];
            const float4 a1 = xt[1 * 64 + l];
            const float4 a2 = xt[2 * 64 + l];
            const float4 a3 = xt[3 * 64 + l];
            nfloat4 o;
            o.x = m4.x * a0.x + m4.y * a1.x + m4.z * a2.x + m4.w * a3.x;
            o.y = m4.x * a0.y + m4.y * a1.y + m4.z * a2.y + m4.w * a3.y;
            o.z = m4.x * a0.z + m4.y * a1.z + m4.z * a2.z + m4.w * a3.z;
            o.w = m4.x * a0.w + m4.y * a1.w + m4.z * a2.w + m4.w * a3.w;
            __builtin_nontemporal_store(o, ((nfloat4*)(out + base)) + i * 256 + w * 64 + l);
        }
        __syncthreads();
    }
}

extern "C" void kernel_launch(void* const* d_in, const int* in_sizes, int n_in,
                              void* d_out, int out_size, void* d_ws, size_t ws_size,
                              hipStream_t stream) {
    const float* x      = (const float*)d_in[0];
    const float* scale  = (const float*)d_in[1];
    const float* w_pre  = (const float*)d_in[2];
    const float* w_post = (const float*)d_in[3];
    const float* w_res  = (const float*)d_in[4];
    const float* a_pre  = (const float*)d_in[5];
    const float* a_post = (const float*)d_in[6];
    const float* a_res  = (const float*)d_in[7];
    const float* b_pre  = (const float*)d_in[8];
    const float* b_post = (const float*)d_in[9];
    const float* b_res  = (const float*)d_in[10];
    float* out = (float*)d_out;

    const int tokens = in_sizes[0] / 1024;   // B*T
    const int rounds = tokens / G;
    const int grid = rounds < 1024 ? rounds : 1024;

    fused_route_mix<<<grid, 256, 0, stream>>>(
        x, scale, w_pre, w_post, w_res,
        a_pre, a_post, a_res, b_pre, b_post, b_res,
        out, rounds);
}